// Round 9
// baseline (18042.412 us; speedup 1.0000x reference)
//
#include <hip/hip_runtime.h>
#include <stdint.h>

#define B_SZ   2048
#define T_ENC  168
#define TEMPD  128
#define HID    1024
#define M_DEC  48
#define NBLK   512

typedef _Float16 f16;
typedef _Float16 half8 __attribute__((ext_vector_type(8)));
typedef float    f32x4 __attribute__((ext_vector_type(4)));

__device__ __forceinline__ float sigf(float x)   { return 1.0f / (1.0f + __expf(-x)); }
__device__ __forceinline__ float tanhf_(float x) { return 2.0f / (1.0f + __expf(-2.0f * x)) - 1.0f; }

// Direct global->LDS, 16B per lane. LDS ptr must be wave-uniform base.
__device__ __forceinline__ void gld16(const void* g, void* l) {
    __builtin_amdgcn_global_load_lds(
        (const __attribute__((address_space(1))) void*)g,
        (__attribute__((address_space(3))) void*)l, 16, 0, 0);
}

// ---------------------------------------------------------------------------
// prep_xseq: temp_seq [B][T][128] fp32 -> xseq [T][B][128] f16
// ---------------------------------------------------------------------------
__global__ void prep_xseq(const float* __restrict__ temp_seq, f16* __restrict__ xseq)
{
    size_t i4 = ((size_t)blockIdx.x * blockDim.x + threadIdx.x) * 4;
    size_t b  = i4 / (T_ENC * TEMPD);
    size_t r  = i4 - b * (T_ENC * TEMPD);
    size_t t  = r >> 7;
    size_t d  = r & 127;
    float4 v = *(const float4*)(temp_seq + i4);
    f16* o = xseq + ((t * B_SZ) + b) * TEMPD + d;
    o[0] = (f16)v.x; o[1] = (f16)v.y; o[2] = (f16)v.z; o[3] = (f16)v.w;
}

// ---------------------------------------------------------------------------
// prep_misc: merged f16 weights [4H][128+1024], fcW f16, biases, wlast
// ---------------------------------------------------------------------------
__global__ void prep_misc(
    const float* __restrict__ encWih, const float* __restrict__ encWhh,
    const float* __restrict__ decWih, const float* __restrict__ decWhh,
    const float* __restrict__ encbih, const float* __restrict__ encbhh,
    const float* __restrict__ decbih, const float* __restrict__ decbhh,
    const float* __restrict__ fcW,
    f16* __restrict__ Wenc, f16* __restrict__ Wdec0, f16* __restrict__ fcWh,
    float* __restrict__ enc_b, float* __restrict__ dec_b, float* __restrict__ wlast)
{
    const int NW = 4 * HID * (TEMPD + HID);
    for (int idx = blockIdx.x * blockDim.x + threadIdx.x; idx < NW;
         idx += gridDim.x * blockDim.x) {
        int j = idx / (TEMPD + HID);
        int k = idx - j * (TEMPD + HID);
        Wenc[idx]  = (f16)(k < TEMPD ? encWih[j * TEMPD + k]
                                     : encWhh[(size_t)j * HID + (k - TEMPD)]);
        Wdec0[idx] = (f16)(k < TEMPD ? decWih[j * (TEMPD + 1) + k]
                                     : decWhh[(size_t)j * HID + (k - TEMPD)]);
        if (idx < TEMPD * HID) fcWh[idx] = (f16)fcW[idx];
        if (idx < 4 * HID) {
            enc_b[idx] = encbih[idx] + encbhh[idx];
            dec_b[idx] = decbih[idx] + decbhh[idx];
            wlast[idx] = decWih[idx * (TEMPD + 1) + TEMPD];
        }
    }
}

// ---------------------------------------------------------------------------
// prep_fold: WdecF = decWhh + decWih_x @ fcW ; biasF = decb + decWih_x @ fcb
// ---------------------------------------------------------------------------
__global__ __launch_bounds__(256)
void prep_fold(
    const float* __restrict__ decWih, const float* __restrict__ decWhh,
    const float* __restrict__ decbih, const float* __restrict__ decbhh,
    const float* __restrict__ fcW,    const float* __restrict__ fcb,
    f16* __restrict__ WdecF, float* __restrict__ biasF)
{
    __shared__ float wih[16][TEMPD];
    __shared__ float fcbL[TEMPD];
    const int tid = threadIdx.x;
    const int j0  = blockIdx.x * 16;
    for (int i = tid; i < 16 * TEMPD; i += 256) {
        int r = i >> 7, p = i & 127;
        wih[r][p] = decWih[(size_t)(j0 + r) * (TEMPD + 1) + p];
    }
    if (tid < TEMPD) fcbL[tid] = fcb[tid];
    __syncthreads();
    for (int kk = 0; kk < 4; ++kk) {
        int k = kk * 256 + tid;
        float acc[16];
        #pragma unroll
        for (int r = 0; r < 16; ++r) acc[r] = decWhh[(size_t)(j0 + r) * HID + k];
        for (int p = 0; p < TEMPD; ++p) {
            float w = fcW[(size_t)p * HID + k];
            #pragma unroll
            for (int r = 0; r < 16; ++r) acc[r] += wih[r][p] * w;
        }
        #pragma unroll
        for (int r = 0; r < 16; ++r) WdecF[(size_t)(j0 + r) * HID + k] = (f16)acc[r];
    }
    if (tid < 16) {
        float b = decbih[j0 + tid] + decbhh[j0 + tid];
        for (int p = 0; p < TEMPD; ++p) b += wih[tid][p] * fcbL[p];
        biasF[j0 + tid] = b;
    }
}

// ---------------------------------------------------------------------------
// prep_tileW: merged W [4096][WS] -> fragment-ordered tiles.
// Frag flat index F = bn*NKC*16 + kc*16 + s*8 + g*2 + wc; half8 addr = F*64+lane.
// Lane holds W[g*1024 + bn*32 + wc*16 + (lane&15)][kc*64 + s*32 + (lane>>4)*8 ..+8].
// ---------------------------------------------------------------------------
__global__ void prep_tileW(const f16* __restrict__ Wsrc, f16* __restrict__ Wt,
                           int NKC, int WS)
{
    int idx = blockIdx.x * blockDim.x + threadIdx.x;
    int total = 32 * NKC * 16 * 64;
    if (idx >= total) return;
    int lane = idx & 63;
    int f    = idx >> 6;
    int wc   = f & 1;
    int g    = (f >> 1) & 3;
    int s    = (f >> 3) & 1;
    int kc   = (f >> 4) % NKC;
    int bn   = (f >> 4) / NKC;
    int row  = g * HID + bn * 32 + wc * 16 + (lane & 15);
    int k0   = kc * 64 + s * 32 + (lane >> 4) * 8;
    *(half8*)(Wt + (size_t)idx * 8) = *(const half8*)(Wsrc + (size_t)row * WS + k0);
}

// ---------------------------------------------------------------------------
// Persistent kernel: all 216 LSTM steps + final fc phase in one PLAIN launch.
// Grid 512 x 256. Co-residency by capacity: __launch_bounds__(256,2) caps
// VGPR<=256 -> 2 blocks/CU; LDS 32KB -> 2/CU; 512 = exact capacity, and a
// persistent grid retires no block before barrier 1, so all 512 are resident.
// Manual device-scope grid barrier (release fence -> ticket -> acquire fence).
// Per-step body identical to verified r7 kernel.
// ---------------------------------------------------------------------------
struct PK {
    const f16* xseq; f16* hA; f16* hB; float* c;
    const f16* WencT; const f16* Wdec0T; const f16* WdecFT;
    const float* enc_b; const float* dec_b; const float* biasF;
    const float* wlast; const float* speeds;
    f16* hist; const f16* fcWh; const float* fcb; float* out;
    unsigned* cnt; unsigned* gen;
};

__device__ __forceinline__ void gridbar(unsigned* cnt, unsigned* gen)
{
    __syncthreads();
    if (threadIdx.x == 0) {
        unsigned g = __hip_atomic_load(gen, __ATOMIC_RELAXED, __HIP_MEMORY_SCOPE_AGENT);
        __builtin_amdgcn_fence(__ATOMIC_RELEASE, "agent");   // flush this XCD's writes
        unsigned a = __hip_atomic_fetch_add(cnt, 1u, __ATOMIC_RELAXED, __HIP_MEMORY_SCOPE_AGENT);
        if (a == NBLK - 1) {
            __hip_atomic_store(cnt, 0u, __ATOMIC_RELAXED, __HIP_MEMORY_SCOPE_AGENT);
            __hip_atomic_store(gen, g + 1u, __ATOMIC_RELEASE, __HIP_MEMORY_SCOPE_AGENT);
        } else {
            long spin = 0;
            while (__hip_atomic_load(gen, __ATOMIC_RELAXED, __HIP_MEMORY_SCOPE_AGENT) == g) {
                __builtin_amdgcn_s_sleep(1);
                if (++spin > 400000) break;   // ~10ms: fail loud, never hang
            }
        }
        __builtin_amdgcn_fence(__ATOMIC_ACQUIRE, "agent");   // invalidate caches before reads
    }
    __syncthreads();
}

__global__ __launch_bounds__(256, 2)
void persist(PK p)
{
    __shared__ half8 smem[2048];   // 32 KB: main loop ldsA[2][1024]; fc {fa 256 | fw 1024}

    const size_t SLOT = (size_t)B_SZ * HID;
    const int tid  = threadIdx.x;
    const int lane = tid & 63;
    const int wid  = tid >> 6;
    const int wr   = wid >> 1;        // 0..1 : 64-row half
    const int wc   = wid & 1;         // 0..1 : 16-col half
    const int id   = blockIdx.x;
    const int swzb = (id & 7) * 64 + (id >> 3);   // bijective XCD swizzle (512 = 8*64)
    const int bn   = swzb >> 4;       // 0..31
    const int bm   = swzb & 15;       // 0..15

    for (int step = 0; step < T_ENC + M_DEC; ++step) {
        const int m = step - T_ENC;
        const f16* Wt; const float* bias; const f16* xsrc;
        const f16* hin; f16* hout;
        int nkc, fullk, dec;
        if (step < T_ENC) {
            Wt = p.WencT; bias = p.enc_b; nkc = 18; fullk = 1; dec = 0;
            xsrc = p.xseq + (size_t)step * (B_SZ * TEMPD);
            hin  = (step & 1) ? p.hB : p.hA;
            hout = (step & 1) ? p.hA : p.hB;
        } else if (m == 0) {
            Wt = p.Wdec0T; bias = p.dec_b; nkc = 18; fullk = 1; dec = 1;
            xsrc = p.xseq + (size_t)(T_ENC - 1) * (B_SZ * TEMPD);
            hin  = p.hA;                       // T_ENC even -> final enc h in hA
            hout = p.hist;
        } else {
            Wt = p.WdecFT; bias = p.biasF; nkc = 16; fullk = 0; dec = 1;
            xsrc = nullptr;
            hin  = p.hist + (size_t)(m - 1) * SLOT;
            hout = p.hist + (size_t)m * SLOT;
        }
        const half8* wtb = (const half8*)Wt + (size_t)bn * nkc * 16 * 64 + wc * 64 + lane;

        f32x4 acc[4][4];
        #pragma unroll
        for (int g = 0; g < 4; ++g)
            #pragma unroll
            for (int mr = 0; mr < 4; ++mr)
                acc[g][mr] = (f32x4){0.f, 0.f, 0.f, 0.f};

        auto stageA = [&](int b, int kc) {
            if (fullk && kc < 2) {
                #pragma unroll
                for (int it = 0; it < 4; ++it) {
                    int pc = wid * 256 + it * 64 + lane;
                    int row = pc >> 3, s = pc & 7;
                    gld16(xsrc + (size_t)(bm * 128 + row) * TEMPD + kc * 64 + ((s ^ (row & 7)) << 3),
                          &smem[b * 1024 + wid * 256 + it * 64]);
                }
            } else {
                const int k0 = kc * 64 - (fullk ? TEMPD : 0);
                #pragma unroll
                for (int it = 0; it < 4; ++it) {
                    int pc = wid * 256 + it * 64 + lane;
                    int row = pc >> 3, s = pc & 7;
                    gld16(hin + (size_t)(bm * 128 + row) * HID + k0 + ((s ^ (row & 7)) << 3),
                          &smem[b * 1024 + wid * 256 + it * 64]);
                }
            }
        };
        auto loadW = [&](half8 (&wf)[8], int kc) {
            const half8* pw = wtb + (size_t)kc * (16 * 64);
            #pragma unroll
            for (int f = 0; f < 8; ++f) wf[f] = pw[f * 128];   // f = s*4+g
        };
        auto compute = [&](int b, const half8 (&wf)[8]) {
            #pragma unroll
            for (int s = 0; s < 2; ++s) {
                const int ks = s * 4 + (lane >> 4);
                half8 af[4];
                #pragma unroll
                for (int mr = 0; mr < 4; ++mr) {
                    int row = wr * 64 + mr * 16 + (lane & 15);
                    af[mr] = smem[b * 1024 + row * 8 + (ks ^ (row & 7))];
                }
                __builtin_amdgcn_s_setprio(1);
                #pragma unroll
                for (int g = 0; g < 4; ++g)
                    #pragma unroll
                    for (int mr = 0; mr < 4; ++mr)
                        acc[g][mr] = __builtin_amdgcn_mfma_f32_16x16x32_f16(af[mr], wf[s * 4 + g], acc[g][mr], 0, 0, 0);
                __builtin_amdgcn_s_setprio(0);
            }
        };

        half8 wfA[8], wfB[8];
        stageA(0, 0); loadW(wfA, 0);
        __syncthreads();
        for (int kc = 0; kc < nkc; kc += 2) {
            stageA(1, kc + 1); loadW(wfB, kc + 1);
            compute(0, wfA);
            __syncthreads();
            if (kc + 2 < nkc) { stageA(0, kc + 2); loadW(wfA, kc + 2); }
            compute(1, wfB);
            __syncthreads();
        }

        // ---- epilogue: LSTM pointwise ----
        const int col_g = bn * 32 + wc * 16 + (lane & 15);
        const float bi  = bias[col_g];
        const float bf_ = bias[HID + col_g];
        const float bg  = bias[2 * HID + col_g];
        const float bo  = bias[3 * HID + col_g];
        float wli = 0.f, wlf = 0.f, wlg = 0.f, wlo = 0.f;
        if (dec) {
            wli = p.wlast[col_g];
            wlf = p.wlast[HID + col_g];
            wlg = p.wlast[2 * HID + col_g];
            wlo = p.wlast[3 * HID + col_g];
        }
        #pragma unroll
        for (int mr = 0; mr < 4; ++mr) {
            #pragma unroll
            for (int q = 0; q < 4; ++q) {
                int row_g = bm * 128 + wr * 64 + mr * 16 + (lane >> 4) * 4 + q;
                float pi = acc[0][mr][q] + bi;
                float pf = acc[1][mr][q] + bf_;
                float pg = acc[2][mr][q] + bg;
                float po = acc[3][mr][q] + bo;
                if (dec) {
                    float sp = p.speeds[(size_t)row_g * M_DEC + m];
                    pi += sp * wli; pf += sp * wlf; pg += sp * wlg; po += sp * wlo;
                }
                float ii = sigf(pi), ff = sigf(pf), gg = tanhf_(pg), oo = sigf(po);
                size_t idx = (size_t)row_g * HID + col_g;
                float cn = ff * p.c[idx] + ii * gg;
                p.c[idx] = cn;
                hout[idx] = (f16)(oo * tanhf_(cn));
            }
        }

        gridbar(p.cnt, p.gen);
    }

    // ---- fc phase: preds[slot] = hist[slot] @ fcW^T + fcb -> d_out ----
    for (int tile = id; tile < M_DEC * 64; tile += NBLK) {
        const int slot = tile >> 6;
        const int b0   = (tile & 63) * 32;
        const f16* hrow = p.hist + (size_t)slot * SLOT + (size_t)b0 * HID;

        f32x4 facc[4];
        #pragma unroll
        for (int nr = 0; nr < 4; ++nr) facc[nr] = (f32x4){0.f, 0.f, 0.f, 0.f};

        for (int kc = 0; kc < HID / 64; ++kc) {
            const int k0 = kc * 64;
            {
                int row = tid >> 3, s = tid & 7;
                gld16(hrow + (size_t)row * HID + k0 + ((s ^ (row & 7)) << 3), &smem[wid * 64]);
            }
            #pragma unroll
            for (int it = 0; it < 4; ++it) {
                int pc = wid * 256 + it * 64 + lane;
                int row = pc >> 3, s = pc & 7;
                gld16(p.fcWh + (size_t)row * HID + k0 + ((s ^ (row & 7)) << 3),
                      &smem[256 + wid * 256 + it * 64]);
            }
            __syncthreads();
            #pragma unroll
            for (int s2 = 0; s2 < 2; ++s2) {
                int arow = wr * 16 + (lane & 15);
                int ks = s2 * 4 + (lane >> 4);
                half8 a = smem[arow * 8 + (ks ^ (arow & 7))];
                #pragma unroll
                for (int nr = 0; nr < 4; ++nr) {
                    int brow = wc * 64 + nr * 16 + (lane & 15);
                    half8 bfr = smem[256 + brow * 8 + (ks ^ (brow & 7))];
                    facc[nr] = __builtin_amdgcn_mfma_f32_16x16x32_f16(a, bfr, facc[nr], 0, 0, 0);
                }
            }
            __syncthreads();
        }
        #pragma unroll
        for (int nr = 0; nr < 4; ++nr)
            #pragma unroll
            for (int q = 0; q < 4; ++q) {
                int rloc = wr * 16 + (lane >> 4) * 4 + q;
                int col  = wc * 64 + nr * 16 + (lane & 15);
                p.out[(size_t)(b0 + rloc) * (M_DEC * TEMPD) + (size_t)slot * TEMPD + col]
                    = facc[nr][q] + p.fcb[col];
            }
    }
}

// ---------------------------------------------------------------------------
extern "C" void kernel_launch(void* const* d_in, const int* in_sizes, int n_in,
                              void* d_out, int out_size, void* d_ws, size_t ws_size,
                              hipStream_t stream)
{
    (void)in_sizes; (void)n_in; (void)out_size; (void)ws_size;
    const float* temp_seq   = (const float*)d_in[0];
    const float* avg_speeds = (const float*)d_in[1];
    const float* enc_Wih    = (const float*)d_in[2];
    const float* enc_Whh    = (const float*)d_in[3];
    const float* enc_bih    = (const float*)d_in[4];
    const float* enc_bhh    = (const float*)d_in[5];
    const float* dec_Wih    = (const float*)d_in[6];
    const float* dec_Whh    = (const float*)d_in[7];
    const float* dec_bih    = (const float*)d_in[8];
    const float* dec_bhh    = (const float*)d_in[9];
    const float* fc_W       = (const float*)d_in[10];
    const float* fc_b       = (const float*)d_in[11];
    float* out = (float*)d_out;

    char* ws = (char*)d_ws;
    size_t off = 0;
    auto alloc = [&](size_t bytes) -> void* {
        void* p = ws + off;
        off += (bytes + 255) & ~(size_t)255;
        return p;
    };
    const size_t SLOT = (size_t)B_SZ * HID;
    f16*   Wenc   = (f16*)alloc((size_t)4 * HID * (TEMPD + HID) * 2);
    f16*   Wdec0  = (f16*)alloc((size_t)4 * HID * (TEMPD + HID) * 2);
    f16*   WdecF  = (f16*)alloc((size_t)4 * HID * HID * 2);
    f16*   WencT  = (f16*)alloc((size_t)32 * 18 * 16 * 64 * 8 * 2);
    f16*   Wdec0T = (f16*)alloc((size_t)32 * 18 * 16 * 64 * 8 * 2);
    f16*   WdecFT = (f16*)alloc((size_t)32 * 16 * 16 * 64 * 8 * 2);
    f16*   fcWh   = (f16*)alloc((size_t)TEMPD * HID * 2);
    float* enc_b  = (float*)alloc((size_t)4 * HID * 4);
    float* dec_b  = (float*)alloc((size_t)4 * HID * 4);
    float* biasF  = (float*)alloc((size_t)4 * HID * 4);
    float* wlast  = (float*)alloc((size_t)4 * HID * 4);
    f16*   hA     = (f16*)alloc(SLOT * 2);
    f16*   hB     = (f16*)alloc(SLOT * 2);
    float* cbuf   = (float*)alloc(SLOT * 4);
    f16*   xseq   = (f16*)alloc((size_t)T_ENC * B_SZ * TEMPD * 2);   // 88 MB
    f16*   hist   = (f16*)alloc((size_t)M_DEC * SLOT * 2);           // 192 MB
    unsigned* bar = (unsigned*)alloc(256);                           // cnt, gen

    hipMemsetAsync(hA,   0, SLOT * 2, stream);
    hipMemsetAsync(cbuf, 0, SLOT * 4, stream);
    hipMemsetAsync(bar,  0, 256, stream);

    prep_xseq<<<(B_SZ * T_ENC * TEMPD / 4 + 255) / 256, 256, 0, stream>>>(temp_seq, xseq);
    prep_misc<<<8192, 256, 0, stream>>>(
        enc_Wih, enc_Whh, dec_Wih, dec_Whh,
        enc_bih, enc_bhh, dec_bih, dec_bhh, fc_W,
        Wenc, Wdec0, fcWh, enc_b, dec_b, wlast);
    prep_fold<<<256, 256, 0, stream>>>(
        dec_Wih, dec_Whh, dec_bih, dec_bhh, fc_W, fc_b, WdecF, biasF);
    prep_tileW<<<(32 * 18 * 16 * 64 + 255) / 256, 256, 0, stream>>>(Wenc,  WencT,  18, TEMPD + HID);
    prep_tileW<<<(32 * 18 * 16 * 64 + 255) / 256, 256, 0, stream>>>(Wdec0, Wdec0T, 18, TEMPD + HID);
    prep_tileW<<<(32 * 16 * 16 * 64 + 255) / 256, 256, 0, stream>>>(WdecF, WdecFT, 16, HID);

    PK pk;
    pk.xseq = xseq; pk.hA = hA; pk.hB = hB; pk.c = cbuf;
    pk.WencT = WencT; pk.Wdec0T = Wdec0T; pk.WdecFT = WdecFT;
    pk.enc_b = enc_b; pk.dec_b = dec_b; pk.biasF = biasF;
    pk.wlast = wlast; pk.speeds = avg_speeds;
    pk.hist = hist; pk.fcWh = fcWh; pk.fcb = fc_b; pk.out = out;
    pk.cnt = bar; pk.gen = bar + 1;

    persist<<<dim3(NBLK), dim3(256), 0, stream>>>(pk);
}

// Round 10
// 8148.880 us; speedup vs baseline: 2.2141x; 2.2141x over previous
//
#include <hip/hip_runtime.h>
#include <stdint.h>

#define B_SZ   2048
#define T_ENC  168
#define TEMPD  128
#define HID    1024
#define M_DEC  48
#define NBLK   512

typedef _Float16 f16;
typedef _Float16 half8 __attribute__((ext_vector_type(8)));
typedef float    f32x4 __attribute__((ext_vector_type(4)));

__device__ __forceinline__ float sigf(float x)   { return 1.0f / (1.0f + __expf(-x)); }
__device__ __forceinline__ float tanhf_(float x) { return 2.0f / (1.0f + __expf(-2.0f * x)) - 1.0f; }

// Direct global->LDS, 16B per lane. AUX = cache policy (0 = cached; 17 = sc0|sc1
// = bypass L1/L2, serve from the coherent memory-side Infinity Cache).
template <int AUX>
__device__ __forceinline__ void gld16(const void* g, void* l) {
    __builtin_amdgcn_global_load_lds(
        (const __attribute__((address_space(1))) void*)g,
        (__attribute__((address_space(3))) void*)l, 16, 0, AUX);
}

// 2-byte store with sc0 sc1: bypasses L1/L2, lands in IF$/memory (coherent).
__device__ __forceinline__ void store_h16(f16* p, f16 v) {
    union { f16 h; unsigned short u; } cv; cv.h = v;
    unsigned v32 = cv.u;
    asm volatile("global_store_short %0, %1, off sc0 sc1" :: "v"(p), "v"(v32) : "memory");
}

// ---------------------------------------------------------------------------
// prep_xseq: temp_seq [B][T][128] fp32 -> xseq [T][B][128] f16
// ---------------------------------------------------------------------------
__global__ void prep_xseq(const float* __restrict__ temp_seq, f16* __restrict__ xseq)
{
    size_t i4 = ((size_t)blockIdx.x * blockDim.x + threadIdx.x) * 4;
    size_t b  = i4 / (T_ENC * TEMPD);
    size_t r  = i4 - b * (T_ENC * TEMPD);
    size_t t  = r >> 7;
    size_t d  = r & 127;
    float4 v = *(const float4*)(temp_seq + i4);
    f16* o = xseq + ((t * B_SZ) + b) * TEMPD + d;
    o[0] = (f16)v.x; o[1] = (f16)v.y; o[2] = (f16)v.z; o[3] = (f16)v.w;
}

// ---------------------------------------------------------------------------
// prep_misc: merged f16 weights [4H][128+1024], fcW f16, biases, wlast
// ---------------------------------------------------------------------------
__global__ void prep_misc(
    const float* __restrict__ encWih, const float* __restrict__ encWhh,
    const float* __restrict__ decWih, const float* __restrict__ decWhh,
    const float* __restrict__ encbih, const float* __restrict__ encbhh,
    const float* __restrict__ decbih, const float* __restrict__ decbhh,
    const float* __restrict__ fcW,
    f16* __restrict__ Wenc, f16* __restrict__ Wdec0, f16* __restrict__ fcWh,
    float* __restrict__ enc_b, float* __restrict__ dec_b, float* __restrict__ wlast)
{
    const int NW = 4 * HID * (TEMPD + HID);
    for (int idx = blockIdx.x * blockDim.x + threadIdx.x; idx < NW;
         idx += gridDim.x * blockDim.x) {
        int j = idx / (TEMPD + HID);
        int k = idx - j * (TEMPD + HID);
        Wenc[idx]  = (f16)(k < TEMPD ? encWih[j * TEMPD + k]
                                     : encWhh[(size_t)j * HID + (k - TEMPD)]);
        Wdec0[idx] = (f16)(k < TEMPD ? decWih[j * (TEMPD + 1) + k]
                                     : decWhh[(size_t)j * HID + (k - TEMPD)]);
        if (idx < TEMPD * HID) fcWh[idx] = (f16)fcW[idx];
        if (idx < 4 * HID) {
            enc_b[idx] = encbih[idx] + encbhh[idx];
            dec_b[idx] = decbih[idx] + decbhh[idx];
            wlast[idx] = decWih[idx * (TEMPD + 1) + TEMPD];
        }
    }
}

// ---------------------------------------------------------------------------
// prep_fold: WdecF = decWhh + decWih_x @ fcW ; biasF = decb + decWih_x @ fcb
// ---------------------------------------------------------------------------
__global__ __launch_bounds__(256)
void prep_fold(
    const float* __restrict__ decWih, const float* __restrict__ decWhh,
    const float* __restrict__ decbih, const float* __restrict__ decbhh,
    const float* __restrict__ fcW,    const float* __restrict__ fcb,
    f16* __restrict__ WdecF, float* __restrict__ biasF)
{
    __shared__ float wih[16][TEMPD];
    __shared__ float fcbL[TEMPD];
    const int tid = threadIdx.x;
    const int j0  = blockIdx.x * 16;
    for (int i = tid; i < 16 * TEMPD; i += 256) {
        int r = i >> 7, p = i & 127;
        wih[r][p] = decWih[(size_t)(j0 + r) * (TEMPD + 1) + p];
    }
    if (tid < TEMPD) fcbL[tid] = fcb[tid];
    __syncthreads();
    for (int kk = 0; kk < 4; ++kk) {
        int k = kk * 256 + tid;
        float acc[16];
        #pragma unroll
        for (int r = 0; r < 16; ++r) acc[r] = decWhh[(size_t)(j0 + r) * HID + k];
        for (int p = 0; p < TEMPD; ++p) {
            float w = fcW[(size_t)p * HID + k];
            #pragma unroll
            for (int r = 0; r < 16; ++r) acc[r] += wih[r][p] * w;
        }
        #pragma unroll
        for (int r = 0; r < 16; ++r) WdecF[(size_t)(j0 + r) * HID + k] = (f16)acc[r];
    }
    if (tid < 16) {
        float b = decbih[j0 + tid] + decbhh[j0 + tid];
        for (int p = 0; p < TEMPD; ++p) b += wih[tid][p] * fcbL[p];
        biasF[j0 + tid] = b;
    }
}

// ---------------------------------------------------------------------------
// prep_tileW: merged W [4096][WS] -> fragment-ordered tiles.
// Frag flat index F = bn*NKC*16 + kc*16 + s*8 + g*2 + wc; half8 addr = F*64+lane.
// ---------------------------------------------------------------------------
__global__ void prep_tileW(const f16* __restrict__ Wsrc, f16* __restrict__ Wt,
                           int NKC, int WS)
{
    int idx = blockIdx.x * blockDim.x + threadIdx.x;
    int total = 32 * NKC * 16 * 64;
    if (idx >= total) return;
    int lane = idx & 63;
    int f    = idx >> 6;
    int wc   = f & 1;
    int g    = (f >> 1) & 3;
    int s    = (f >> 3) & 1;
    int kc   = (f >> 4) % NKC;
    int bn   = (f >> 4) / NKC;
    int row  = g * HID + bn * 32 + wc * 16 + (lane & 15);
    int k0   = kc * 64 + s * 32 + (lane >> 4) * 8;
    *(half8*)(Wt + (size_t)idx * 8) = *(const half8*)(Wsrc + (size_t)row * WS + k0);
}

// ---------------------------------------------------------------------------
// Persistent kernel. Coherence design: W/x/bias/c use normal cached loads and
// are NEVER invalidated (no fences) -> W panels stay L2-resident all 216 steps.
// Cross-XCD h/hist traffic goes through the coherent memory-side IF$ via
// sc0|sc1 stores + sc0|sc1 global_load_lds. Grid barrier = syncthreads (drains
// vmcnt -> sc1 stores visible) + monotonic 2-level ticket, no cache fences.
// ---------------------------------------------------------------------------
struct PK {
    const f16* xseq; f16* hA; f16* hB; float* c;
    const f16* WencT; const f16* Wdec0T; const f16* WdecFT;
    const float* enc_b; const float* dec_b; const float* biasF;
    const float* wlast; const float* speeds;
    f16* hist; const f16* fcWh; const float* fcb; float* out;
    unsigned* bar;   // [0..7]*32: per-XCD cnt lines; [256]: gcnt; [288]: gen
};

__device__ __forceinline__ void gridbar(unsigned* bar, int xcd, unsigned target)
{
    __syncthreads();   // compiler drains vmcnt(0) per wave -> h stores at IF$
    if (threadIdx.x == 0) {
        unsigned a = __hip_atomic_fetch_add(&bar[xcd * 32], 1u,
                        __ATOMIC_RELAXED, __HIP_MEMORY_SCOPE_AGENT);
        if (((a + 1) & 63) == 0) {                 // last of this XCD's 64 blocks
            unsigned b = __hip_atomic_fetch_add(&bar[256], 1u,
                            __ATOMIC_RELAXED, __HIP_MEMORY_SCOPE_AGENT);
            if (((b + 1) & 7) == 0)                // last XCD
                __hip_atomic_store(&bar[288], target,
                    __ATOMIC_RELAXED, __HIP_MEMORY_SCOPE_AGENT);
        }
        long spin = 0;
        while (__hip_atomic_load(&bar[288], __ATOMIC_RELAXED,
                                 __HIP_MEMORY_SCOPE_AGENT) < target) {
            __builtin_amdgcn_s_sleep(1);
            if (++spin > 400000) break;            // fail loud, never hang
        }
        asm volatile("" ::: "memory");
    }
    __syncthreads();
}

__global__ __launch_bounds__(256, 2)
void persist(PK p)
{
    __shared__ half8 smem[2048];   // 32 KB: main loop ldsA[2][1024]; fc {fa|fw}

    const size_t SLOT = (size_t)B_SZ * HID;
    const int tid  = threadIdx.x;
    const int lane = tid & 63;
    const int wid  = tid >> 6;
    const int wr   = wid >> 1;        // 0..1 : 64-row half
    const int wc   = wid & 1;         // 0..1 : 16-col half
    const int id   = blockIdx.x;
    const int xcd  = id & 7;
    const int swzb = xcd * 64 + (id >> 3);        // bijective XCD swizzle
    const int bn   = swzb >> 4;       // 0..31
    const int bm   = swzb & 15;       // 0..15

    for (int step = 0; step < T_ENC + M_DEC; ++step) {
        const int m = step - T_ENC;
        const f16* Wt; const float* bias; const f16* xsrc;
        const f16* hin; f16* hout;
        int nkc, fullk, dec;
        if (step < T_ENC) {
            Wt = p.WencT; bias = p.enc_b; nkc = 18; fullk = 1; dec = 0;
            xsrc = p.xseq + (size_t)step * (B_SZ * TEMPD);
            hin  = (step & 1) ? p.hB : p.hA;
            hout = (step & 1) ? p.hA : p.hB;
        } else if (m == 0) {
            Wt = p.Wdec0T; bias = p.dec_b; nkc = 18; fullk = 1; dec = 1;
            xsrc = p.xseq + (size_t)(T_ENC - 1) * (B_SZ * TEMPD);
            hin  = p.hA;                       // T_ENC even -> final enc h in hA
            hout = p.hist;
        } else {
            Wt = p.WdecFT; bias = p.biasF; nkc = 16; fullk = 0; dec = 1;
            xsrc = nullptr;
            hin  = p.hist + (size_t)(m - 1) * SLOT;
            hout = p.hist + (size_t)m * SLOT;
        }
        const half8* wtb = (const half8*)Wt + (size_t)bn * nkc * 16 * 64 + wc * 64 + lane;

        f32x4 acc[4][4];
        #pragma unroll
        for (int g = 0; g < 4; ++g)
            #pragma unroll
            for (int mr = 0; mr < 4; ++mr)
                acc[g][mr] = (f32x4){0.f, 0.f, 0.f, 0.f};

        auto stageA = [&](int b, int kc) {
            if (fullk && kc < 2) {
                #pragma unroll
                for (int it = 0; it < 4; ++it) {
                    int pc = wid * 256 + it * 64 + lane;
                    int row = pc >> 3, s = pc & 7;
                    gld16<0>(xsrc + (size_t)(bm * 128 + row) * TEMPD + kc * 64 + ((s ^ (row & 7)) << 3),
                             &smem[b * 1024 + wid * 256 + it * 64]);
                }
            } else {
                const int k0 = kc * 64 - (fullk ? TEMPD : 0);
                #pragma unroll
                for (int it = 0; it < 4; ++it) {
                    int pc = wid * 256 + it * 64 + lane;
                    int row = pc >> 3, s = pc & 7;
                    // h: bypass L1/L2 (sc0|sc1=17) -> coherent IF$ read
                    gld16<17>(hin + (size_t)(bm * 128 + row) * HID + k0 + ((s ^ (row & 7)) << 3),
                              &smem[b * 1024 + wid * 256 + it * 64]);
                }
            }
        };
        auto loadW = [&](half8 (&wf)[8], int kc) {
            const half8* pw = wtb + (size_t)kc * (16 * 64);
            #pragma unroll
            for (int f = 0; f < 8; ++f) wf[f] = pw[f * 128];   // f = s*4+g
        };
        auto compute = [&](int b, const half8 (&wf)[8]) {
            #pragma unroll
            for (int s = 0; s < 2; ++s) {
                const int ks = s * 4 + (lane >> 4);
                half8 af[4];
                #pragma unroll
                for (int mr = 0; mr < 4; ++mr) {
                    int row = wr * 64 + mr * 16 + (lane & 15);
                    af[mr] = smem[b * 1024 + row * 8 + (ks ^ (row & 7))];
                }
                __builtin_amdgcn_s_setprio(1);
                #pragma unroll
                for (int g = 0; g < 4; ++g)
                    #pragma unroll
                    for (int mr = 0; mr < 4; ++mr)
                        acc[g][mr] = __builtin_amdgcn_mfma_f32_16x16x32_f16(af[mr], wf[s * 4 + g], acc[g][mr], 0, 0, 0);
                __builtin_amdgcn_s_setprio(0);
            }
        };

        half8 wfA[8], wfB[8];
        stageA(0, 0); loadW(wfA, 0);
        __syncthreads();
        for (int kc = 0; kc < nkc; kc += 2) {
            stageA(1, kc + 1); loadW(wfB, kc + 1);
            compute(0, wfA);
            __syncthreads();
            if (kc + 2 < nkc) { stageA(0, kc + 2); loadW(wfA, kc + 2); }
            compute(1, wfB);
            __syncthreads();
        }

        // ---- epilogue: LSTM pointwise; h stored via sc0sc1 (IF$), c cached ----
        const int col_g = bn * 32 + wc * 16 + (lane & 15);
        const float bi  = bias[col_g];
        const float bf_ = bias[HID + col_g];
        const float bg  = bias[2 * HID + col_g];
        const float bo  = bias[3 * HID + col_g];
        float wli = 0.f, wlf = 0.f, wlg = 0.f, wlo = 0.f;
        if (dec) {
            wli = p.wlast[col_g];
            wlf = p.wlast[HID + col_g];
            wlg = p.wlast[2 * HID + col_g];
            wlo = p.wlast[3 * HID + col_g];
        }
        #pragma unroll
        for (int mr = 0; mr < 4; ++mr) {
            #pragma unroll
            for (int q = 0; q < 4; ++q) {
                int row_g = bm * 128 + wr * 64 + mr * 16 + (lane >> 4) * 4 + q;
                float pi = acc[0][mr][q] + bi;
                float pf = acc[1][mr][q] + bf_;
                float pg = acc[2][mr][q] + bg;
                float po = acc[3][mr][q] + bo;
                if (dec) {
                    float sp = p.speeds[(size_t)row_g * M_DEC + m];
                    pi += sp * wli; pf += sp * wlf; pg += sp * wlg; po += sp * wlo;
                }
                float ii = sigf(pi), ff = sigf(pf), gg = tanhf_(pg), oo = sigf(po);
                size_t idx = (size_t)row_g * HID + col_g;
                float cn = ff * p.c[idx] + ii * gg;
                p.c[idx] = cn;
                store_h16(hout + idx, (f16)(oo * tanhf_(cn)));
            }
        }

        gridbar(p.bar, xcd, (unsigned)(step + 1));
    }

    // ---- fc phase: preds[slot] = hist[slot] @ fcW^T + fcb -> d_out ----
    for (int tile = id; tile < M_DEC * 64; tile += NBLK) {
        const int slot = tile >> 6;
        const int b0   = (tile & 63) * 32;
        const f16* hrow = p.hist + (size_t)slot * SLOT + (size_t)b0 * HID;

        f32x4 facc[4];
        #pragma unroll
        for (int nr = 0; nr < 4; ++nr) facc[nr] = (f32x4){0.f, 0.f, 0.f, 0.f};

        for (int kc = 0; kc < HID / 64; ++kc) {
            const int k0 = kc * 64;
            {
                int row = tid >> 3, s = tid & 7;
                gld16<0>(hrow + (size_t)row * HID + k0 + ((s ^ (row & 7)) << 3), &smem[wid * 64]);
            }
            #pragma unroll
            for (int it = 0; it < 4; ++it) {
                int pc = wid * 256 + it * 64 + lane;
                int row = pc >> 3, s = pc & 7;
                gld16<0>(p.fcWh + (size_t)row * HID + k0 + ((s ^ (row & 7)) << 3),
                         &smem[256 + wid * 256 + it * 64]);
            }
            __syncthreads();
            #pragma unroll
            for (int s2 = 0; s2 < 2; ++s2) {
                int arow = wr * 16 + (lane & 15);
                int ks = s2 * 4 + (lane >> 4);
                half8 a = smem[arow * 8 + (ks ^ (arow & 7))];
                #pragma unroll
                for (int nr = 0; nr < 4; ++nr) {
                    int brow = wc * 64 + nr * 16 + (lane & 15);
                    half8 bfr = smem[256 + brow * 8 + (ks ^ (brow & 7))];
                    facc[nr] = __builtin_amdgcn_mfma_f32_16x16x32_f16(a, bfr, facc[nr], 0, 0, 0);
                }
            }
            __syncthreads();
        }
        #pragma unroll
        for (int nr = 0; nr < 4; ++nr)
            #pragma unroll
            for (int q = 0; q < 4; ++q) {
                int rloc = wr * 16 + (lane >> 4) * 4 + q;
                int col  = wc * 64 + nr * 16 + (lane & 15);
                p.out[(size_t)(b0 + rloc) * (M_DEC * TEMPD) + (size_t)slot * TEMPD + col]
                    = facc[nr][q] + p.fcb[col];
            }
    }
}

// ---------------------------------------------------------------------------
extern "C" void kernel_launch(void* const* d_in, const int* in_sizes, int n_in,
                              void* d_out, int out_size, void* d_ws, size_t ws_size,
                              hipStream_t stream)
{
    (void)in_sizes; (void)n_in; (void)out_size; (void)ws_size;
    const float* temp_seq   = (const float*)d_in[0];
    const float* avg_speeds = (const float*)d_in[1];
    const float* enc_Wih    = (const float*)d_in[2];
    const float* enc_Whh    = (const float*)d_in[3];
    const float* enc_bih    = (const float*)d_in[4];
    const float* enc_bhh    = (const float*)d_in[5];
    const float* dec_Wih    = (const float*)d_in[6];
    const float* dec_Whh    = (const float*)d_in[7];
    const float* dec_bih    = (const float*)d_in[8];
    const float* dec_bhh    = (const float*)d_in[9];
    const float* fc_W       = (const float*)d_in[10];
    const float* fc_b       = (const float*)d_in[11];
    float* out = (float*)d_out;

    char* ws = (char*)d_ws;
    size_t off = 0;
    auto alloc = [&](size_t bytes) -> void* {
        void* p = ws + off;
        off += (bytes + 255) & ~(size_t)255;
        return p;
    };
    const size_t SLOT = (size_t)B_SZ * HID;
    f16*   Wenc   = (f16*)alloc((size_t)4 * HID * (TEMPD + HID) * 2);
    f16*   Wdec0  = (f16*)alloc((size_t)4 * HID * (TEMPD + HID) * 2);
    f16*   WdecF  = (f16*)alloc((size_t)4 * HID * HID * 2);
    f16*   WencT  = (f16*)alloc((size_t)32 * 18 * 16 * 64 * 8 * 2);
    f16*   Wdec0T = (f16*)alloc((size_t)32 * 18 * 16 * 64 * 8 * 2);
    f16*   WdecFT = (f16*)alloc((size_t)32 * 16 * 16 * 64 * 8 * 2);
    f16*   fcWh   = (f16*)alloc((size_t)TEMPD * HID * 2);
    float* enc_b  = (float*)alloc((size_t)4 * HID * 4);
    float* dec_b  = (float*)alloc((size_t)4 * HID * 4);
    float* biasF  = (float*)alloc((size_t)4 * HID * 4);
    float* wlast  = (float*)alloc((size_t)4 * HID * 4);
    f16*   hA     = (f16*)alloc(SLOT * 2);
    f16*   hB     = (f16*)alloc(SLOT * 2);
    float* cbuf   = (float*)alloc(SLOT * 4);
    f16*   xseq   = (f16*)alloc((size_t)T_ENC * B_SZ * TEMPD * 2);   // 88 MB
    f16*   hist   = (f16*)alloc((size_t)M_DEC * SLOT * 2);           // 192 MB
    unsigned* bar = (unsigned*)alloc(4096);   // [xcd*32] cnts, [256] gcnt, [288] gen

    hipMemsetAsync(hA,   0, SLOT * 2, stream);
    hipMemsetAsync(cbuf, 0, SLOT * 4, stream);
    hipMemsetAsync(bar,  0, 4096, stream);

    prep_xseq<<<(B_SZ * T_ENC * TEMPD / 4 + 255) / 256, 256, 0, stream>>>(temp_seq, xseq);
    prep_misc<<<8192, 256, 0, stream>>>(
        enc_Wih, enc_Whh, dec_Wih, dec_Whh,
        enc_bih, enc_bhh, dec_bih, dec_bhh, fc_W,
        Wenc, Wdec0, fcWh, enc_b, dec_b, wlast);
    prep_fold<<<256, 256, 0, stream>>>(
        dec_Wih, dec_Whh, dec_bih, dec_bhh, fc_W, fc_b, WdecF, biasF);
    prep_tileW<<<(32 * 18 * 16 * 64 + 255) / 256, 256, 0, stream>>>(Wenc,  WencT,  18, TEMPD + HID);
    prep_tileW<<<(32 * 18 * 16 * 64 + 255) / 256, 256, 0, stream>>>(Wdec0, Wdec0T, 18, TEMPD + HID);
    prep_tileW<<<(32 * 16 * 16 * 64 + 255) / 256, 256, 0, stream>>>(WdecF, WdecFT, 16, HID);

    PK pk;
    pk.xseq = xseq; pk.hA = hA; pk.hB = hB; pk.c = cbuf;
    pk.WencT = WencT; pk.Wdec0T = Wdec0T; pk.WdecFT = WdecFT;
    pk.enc_b = enc_b; pk.dec_b = dec_b; pk.biasF = biasF;
    pk.wlast = wlast; pk.speeds = avg_speeds;
    pk.hist = hist; pk.fcWh = fcWh; pk.fcb = fc_b; pk.out = out;
    pk.bar = bar;

    persist<<<dim3(NBLK), dim3(256), 0, stream>>>(pk);
}